// Round 4
// baseline (122.666 us; speedup 1.0000x reference)
//
#include <hip/hip_runtime.h>

// B=16, N=1024, M=8192.
//   d[b,n,m] = || binder[b,n,:] - target[m,:] ||
//   attract[b] = mean of 204 smallest (min_m d) over n;  repel[b] = sum relu(3-d)^2
//   out[b] = 10*attract + 5*repel
//
// R6 change (R5 post-mortem: read-filter cut atomics only 35% -- all 128
// chunk-blocks per b are co-resident, so filter reads see near-initial values
// and still fire; dur invariant at 45-51us across VALUBusy 73/41/37% => the
// cross-block atomic fold itself is the structural bottleneck):
//  - ELIMINATE the fold. Each (b,n) min over ALL M computed inside one block:
//    grid (16 n-blocks, 16 b) x 512 thr; thread owns n-point (t&63) and
//    M-slice (t>>6, 1024 targets). All 8192 transformed targets staged in
//    128KB LDS; inner loop = uniform ds_read_b128 (broadcast) + 3fma + min.
//  - 8 slice-partials folded via LDS (aliased over target buffer), plain
//    float d^2 store. No atomics, no memset, no key encode/decode.
//  - reduce kernel selects on raw d^2 bits; repel_part shrinks 128->16.

#define BB 16
#define NN 1024
#define MM 8192
#define NB 64               // n-points per block
#define NBLK (NN / NB)      // 16 n-blocks per b
#define THREADS 512
#define SLICES (THREADS / NB)   // 8 M-slices per block
#define MSL (MM / SLICES)       // 1024 targets per slice
#define KSEL 204            // int(0.2 * 1024)

__global__ __launch_bounds__(THREADS, 1) void binder_pair_kernel(
    const float* __restrict__ binder,   // [B, N, 3]
    const float* __restrict__ target,   // [M, 3]
    float* __restrict__ min_d2,         // [B, N] min d^2 (plain store)
    float* __restrict__ repel_part)     // [B, NBLK]
{
    __shared__ float4 t4[MM];           // 128 KB: (-2tx, -2ty, -2tz, ||t||^2)
    __shared__ float wred[SLICES];

    const int nb  = blockIdx.x;
    const int b   = blockIdx.y;
    const int tid = threadIdx.x;

    // stage all transformed targets (96 KB read, L2/L3-resident across blocks)
    for (int i = tid; i < MM; i += THREADS) {
        const float tx = target[i * 3 + 0];
        const float ty = target[i * 3 + 1];
        const float tz = target[i * 3 + 2];
        t4[i] = make_float4(-2.0f * tx, -2.0f * ty, -2.0f * tz,
                            fmaf(tx, tx, fmaf(ty, ty, tz * tz)));
    }
    __syncthreads();

    const int n = tid & (NB - 1);       // n-point within block (lane id)
    const int q = tid >> 6;             // M-slice == wave id
    const float* bp = binder + ((size_t)b * NN + nb * NB + n) * 3;
    const float x = bp[0], y = bp[1], z = bp[2];
    const float bb = fmaf(x, x, fmaf(y, y, z * z));
    const float th = 9.0f - bb;         // e < th  <=>  d^2 < 9

    float me    = 3.4e38f;
    float repel = 0.0f;
    const int m0 = q * MSL;
#pragma unroll 4
    for (int m = m0; m < m0 + MSL; ++m) {
        const float4 t = t4[m];         // wave-uniform addr -> broadcast b128
        const float e = fmaf(x, t.x, fmaf(y, t.y, fmaf(z, t.z, t.w)));
        me = fminf(me, e);
        // clash: ~15%-taken wave-uniform branch; non-clash lanes clamp to 0.
        if (__any(e < th)) {
            const float c = fmaxf(3.0f - __builtin_amdgcn_sqrtf(fmaxf(bb + e, 0.0f)), 0.0f);
            repel = fmaf(c, c, repel);
        }
    }

    __syncthreads();                    // all waves done reading t4
    float* pe = (float*)t4;             // alias: [SLICES][NB] partial e-mins
    pe[q * NB + n] = me;

    // repel: wave shuffle-reduce, one slot per wave
#pragma unroll
    for (int off = 32; off > 0; off >>= 1) repel += __shfl_down(repel, off);
    if (n == 0) wred[q] = repel;
    __syncthreads();

    if (tid < NB) {                     // wave 0: fold 8 slice partials
        float mn = pe[tid];
#pragma unroll
        for (int qq = 1; qq < SLICES; ++qq) mn = fminf(mn, pe[qq * NB + tid]);
        min_d2[(size_t)b * NN + nb * NB + tid] = fmaxf(bb + mn, 0.0f);
    }
    if (tid == 0) {
        float r = 0.0f;
#pragma unroll
        for (int w = 0; w < SLICES; ++w) r += wred[w];
        repel_part[b * NBLK + nb] = r;
    }
}

__global__ __launch_bounds__(256) void binder_reduce_kernel(
    const float* __restrict__ min_d2,      // [B, N] (nonneg -> bits monotonic)
    const float* __restrict__ repel_part,  // [B, NBLK]
    float* __restrict__ out)               // [B]
{
    __shared__ int cnt[256];
    __shared__ int wsum[4];
    __shared__ int bc_bin, bc_rem;
    __shared__ float wred[4];
    __shared__ float wred2[4];

    const int b    = blockIdx.x;
    const int tid  = threadIdx.x;
    const int lane = tid & 63;
    const int wid  = tid >> 6;

    const uint4 kv = ((const uint4*)(min_d2 + (size_t)b * NN))[tid];
    const unsigned uu[4] = {kv.x, kv.y, kv.z, kv.w};

    // radix-256 select of the KSEL-th smallest d^2 bit pattern, MSB-first.
    // scan per round: intra-wave __shfl_up inclusive scan (no barriers) +
    // 4-entry wave-sum combine -> 4 barriers/round.
    unsigned prefix = 0u;
    int rem = KSEL;
#pragma unroll
    for (int shift = 24; shift >= 0; shift -= 8) {
        cnt[tid] = 0;
        __syncthreads();
        const unsigned hmask = (shift == 24) ? 0u : (0xFFFFFFFFu << (shift + 8));
#pragma unroll
        for (int p = 0; p < 4; ++p)
            if ((uu[p] & hmask) == (prefix & hmask))
                atomicAdd(&cnt[(uu[p] >> shift) & 255], 1);
        __syncthreads();
        const int orig = cnt[tid];
        int v = orig;
#pragma unroll
        for (int s = 1; s < 64; s <<= 1) {
            const int t = __shfl_up(v, s);
            if (lane >= s) v += t;
        }
        if (lane == 63) wsum[wid] = v;
        __syncthreads();
        int off = 0;
        for (int w = 0; w < wid; ++w) off += wsum[w];
        const int incl = v + off;
        const int excl = incl - orig;
        if (rem > excl && rem <= incl) {   // unique tid (orig>0 there)
            bc_bin = tid;
            bc_rem = rem - excl;
        }
        __syncthreads();
        prefix |= ((unsigned)bc_bin) << shift;
        rem = bc_rem;
        __syncthreads();
    }
    // prefix = T (exact bits of KSEL-th smallest d2); rem = #ties to take.

    float local = 0.0f;
#pragma unroll
    for (int p = 0; p < 4; ++p)
        if (uu[p] < prefix) local += __builtin_amdgcn_sqrtf(__uint_as_float(uu[p]));
#pragma unroll
    for (int off = 32; off > 0; off >>= 1) local += __shfl_down(local, off);
    if ((tid & 63) == 0) wred[tid >> 6] = local;

    float r = (tid < NBLK) ? repel_part[b * NBLK + tid] : 0.0f;
#pragma unroll
    for (int off = 32; off > 0; off >>= 1) r += __shfl_down(r, off);
    if ((tid & 63) == 0) wred2[tid >> 6] = r;
    __syncthreads();

    if (tid == 0) {
        const float total = wred[0] + wred[1] + wred[2] + wred[3]
                          + (float)rem * __builtin_amdgcn_sqrtf(__uint_as_float(prefix));
        const float rp = wred2[0] + wred2[1] + wred2[2] + wred2[3];
        out[b] = 10.0f * (total / (float)KSEL) + 5.0f * rp;
    }
}

extern "C" void kernel_launch(void* const* d_in, const int* in_sizes, int n_in,
                              void* d_out, int out_size, void* d_ws, size_t ws_size,
                              hipStream_t stream) {
    const float* binder = (const float*)d_in[0];   // [16,1024,3] fp32
    const float* target = (const float*)d_in[1];   // [8192,3]   fp32
    float* out = (float*)d_out;                    // [16]       fp32

    float* min_d2     = (float*)d_ws;                                   // 64 KB
    float* repel_part = (float*)((char*)d_ws + (size_t)BB * NN * sizeof(float));

    dim3 g1(NBLK, BB);   // 16 x 16 = 256 blocks (1/CU), 512 threads
    binder_pair_kernel<<<g1, THREADS, 0, stream>>>(binder, target, min_d2, repel_part);
    binder_reduce_kernel<<<BB, 256, 0, stream>>>(min_d2, repel_part, out);
}

// Round 5
// 102.318 us; speedup vs baseline: 1.1989x; 1.1989x over previous
//
#include <hip/hip_runtime.h>

// B=16, N=1024, M=8192.
//   d[b,n,m] = || binder[b,n,:] - target[m,:] ||
//   attract[b] = mean of 204 smallest (min_m d) over n;  repel[b] = sum relu(3-d)^2
//   out[b] = 10*attract + 5*repel
//
// R7 (R6 post-mortem: WRITE_SIZE 21MB->72KB confirmed the atomic-fold theory,
// but 128KB LDS -> 1 block/CU (occ 20%) and 1 pt/thread -> 1 ds_read_b128 per
// ~5 VALU made the loop LDS-rate-bound: 69us, VALUBusy 27%):
//  - keep: NO global atomics, NO memset. fold via plain stores + reduce-side min.
//  - restore R4 loop shape: 4 n-points/thread, ~20 VALU per broadcast b128 read.
//  - SL=32 M-slices of 256 targets; grid (32,16) x 256thr = 512 blocks,
//    2 blocks/CU, 8 waves/CU, 4KB LDS.
//  - pair stores partial d^2 [B][SL][N] as coalesced float4 (2MB streaming).
//  - reduce folds 32 slices in its load phase (32 coalesced float4 loads),
//    then radix-256 select on raw d^2 bits (nonneg -> monotonic).

#define BB 16
#define NN 1024
#define MM 8192
#define SL 32               // M-slices
#define MSL (MM / SL)       // 256 targets per slice
#define KSEL 204            // int(0.2 * 1024)

__global__ __launch_bounds__(256, 4) void binder_pair_kernel(
    const float* __restrict__ binder,    // [B, N, 3]
    const float* __restrict__ target,    // [M, 3]
    float* __restrict__ min_part,        // [B, SL, N] partial min d^2
    float* __restrict__ repel_part)      // [B, SL]
{
    __shared__ float4 t4[MSL];           // 4KB: (-2tx, -2ty, -2tz, ||t||^2)
    __shared__ float wred[4];

    const int s   = blockIdx.x;
    const int b   = blockIdx.y;
    const int tid = threadIdx.x;

    // stage this slice's 256 transformed targets (one per thread)
    {
        const float* tp = target + (size_t)(s * MSL + tid) * 3;
        const float tx = tp[0], ty = tp[1], tz = tp[2];
        t4[tid] = make_float4(-2.0f * tx, -2.0f * ty, -2.0f * tz,
                              fmaf(tx, tx, fmaf(ty, ty, tz * tz)));
    }
    __syncthreads();

    // 4 binder points per thread; 48B contiguous/lane, 16B-aligned.
    const float* bp = binder + ((size_t)b * NN + tid * 4) * 3;
    const float4 f0 = ((const float4*)bp)[0];
    const float4 f1 = ((const float4*)bp)[1];
    const float4 f2 = ((const float4*)bp)[2];
    const float x0 = f0.x, y0 = f0.y, z0 = f0.z;
    const float x1 = f0.w, y1 = f1.x, z1 = f1.y;
    const float x2 = f1.z, y2 = f1.w, z2 = f2.x;
    const float x3 = f2.y, y3 = f2.z, z3 = f2.w;

    const float bb0 = fmaf(x0, x0, fmaf(y0, y0, z0 * z0));
    const float bb1 = fmaf(x1, x1, fmaf(y1, y1, z1 * z1));
    const float bb2 = fmaf(x2, x2, fmaf(y2, y2, z2 * z2));
    const float bb3 = fmaf(x3, x3, fmaf(y3, y3, z3 * z3));
    const float th0 = 9.0f - bb0, th1 = 9.0f - bb1;
    const float th2 = 9.0f - bb2, th3 = 9.0f - bb3;

    float m0 = 3.4e38f, m1 = 3.4e38f, m2 = 3.4e38f, m3 = 3.4e38f;
    float repel = 0.0f;

#pragma unroll 4
    for (int m = 0; m < MSL; ++m) {
        const float4 t = t4[m];   // wave-uniform addr -> broadcast b128
        const float e0 = fmaf(x0, t.x, fmaf(y0, t.y, fmaf(z0, t.z, t.w)));
        const float e1 = fmaf(x1, t.x, fmaf(y1, t.y, fmaf(z1, t.z, t.w)));
        const float e2 = fmaf(x2, t.x, fmaf(y2, t.y, fmaf(z2, t.z, t.w)));
        const float e3 = fmaf(x3, t.x, fmaf(y3, t.y, fmaf(z3, t.z, t.w)));
        m0 = fminf(m0, e0);
        m1 = fminf(m1, e1);
        m2 = fminf(m2, e2);
        m3 = fminf(m3, e3);
        // per-point clash: e < 9-bb <=> d^2 < 9; non-clash lanes clamp to 0.
        if (__any(e0 < th0)) {
            const float c = fmaxf(3.0f - __builtin_amdgcn_sqrtf(fmaxf(bb0 + e0, 0.0f)), 0.0f);
            repel = fmaf(c, c, repel);
        }
        if (__any(e1 < th1)) {
            const float c = fmaxf(3.0f - __builtin_amdgcn_sqrtf(fmaxf(bb1 + e1, 0.0f)), 0.0f);
            repel = fmaf(c, c, repel);
        }
        if (__any(e2 < th2)) {
            const float c = fmaxf(3.0f - __builtin_amdgcn_sqrtf(fmaxf(bb2 + e2, 0.0f)), 0.0f);
            repel = fmaf(c, c, repel);
        }
        if (__any(e3 < th3)) {
            const float c = fmaxf(3.0f - __builtin_amdgcn_sqrtf(fmaxf(bb3 + e3, 0.0f)), 0.0f);
            repel = fmaf(c, c, repel);
        }
    }

    // plain coalesced store of this slice's partial min d^2 (no atomics)
    float4* op = (float4*)(min_part + ((size_t)b * SL + s) * NN) + tid;
    *op = make_float4(fmaxf(bb0 + m0, 0.0f), fmaxf(bb1 + m1, 0.0f),
                      fmaxf(bb2 + m2, 0.0f), fmaxf(bb3 + m3, 0.0f));

    // repel block-reduce: wave shuffle then 4-slot LDS
#pragma unroll
    for (int off = 32; off > 0; off >>= 1) repel += __shfl_down(repel, off);
    if ((tid & 63) == 0) wred[tid >> 6] = repel;
    __syncthreads();
    if (tid == 0) repel_part[b * SL + s] = wred[0] + wred[1] + wred[2] + wred[3];
}

__global__ __launch_bounds__(256) void binder_reduce_kernel(
    const float* __restrict__ min_part,    // [B, SL, N]
    const float* __restrict__ repel_part,  // [B, SL]
    float* __restrict__ out)               // [B]
{
    __shared__ int cnt[256];
    __shared__ int wsum[4];
    __shared__ int bc_bin, bc_rem;
    __shared__ float wred[4];
    __shared__ float wred2[4];

    const int b    = blockIdx.x;
    const int tid  = threadIdx.x;
    const int lane = tid & 63;
    const int wid  = tid >> 6;

    // fold the SL slice partials during load (coalesced float4 per slice row)
    const float* base = min_part + (size_t)b * SL * NN;
    float mn0 = 3.4e38f, mn1 = 3.4e38f, mn2 = 3.4e38f, mn3 = 3.4e38f;
#pragma unroll
    for (int s = 0; s < SL; ++s) {
        const float4 v = ((const float4*)(base + (size_t)s * NN))[tid];
        mn0 = fminf(mn0, v.x);
        mn1 = fminf(mn1, v.y);
        mn2 = fminf(mn2, v.z);
        mn3 = fminf(mn3, v.w);
    }
    const unsigned uu[4] = {__float_as_uint(mn0), __float_as_uint(mn1),
                            __float_as_uint(mn2), __float_as_uint(mn3)};

    // radix-256 select of the KSEL-th smallest d^2 bit pattern, MSB-first.
    // scan per round: intra-wave __shfl_up inclusive scan (no barriers) +
    // 4-entry wave-sum combine -> 4 barriers/round.
    unsigned prefix = 0u;
    int rem = KSEL;
#pragma unroll
    for (int shift = 24; shift >= 0; shift -= 8) {
        cnt[tid] = 0;
        __syncthreads();
        const unsigned hmask = (shift == 24) ? 0u : (0xFFFFFFFFu << (shift + 8));
#pragma unroll
        for (int p = 0; p < 4; ++p)
            if ((uu[p] & hmask) == (prefix & hmask))
                atomicAdd(&cnt[(uu[p] >> shift) & 255], 1);
        __syncthreads();
        const int orig = cnt[tid];
        int v = orig;
#pragma unroll
        for (int s = 1; s < 64; s <<= 1) {
            const int t = __shfl_up(v, s);
            if (lane >= s) v += t;
        }
        if (lane == 63) wsum[wid] = v;
        __syncthreads();
        int off = 0;
        for (int w = 0; w < wid; ++w) off += wsum[w];
        const int incl = v + off;
        const int excl = incl - orig;
        if (rem > excl && rem <= incl) {   // unique tid (orig>0 there)
            bc_bin = tid;
            bc_rem = rem - excl;
        }
        __syncthreads();
        prefix |= ((unsigned)bc_bin) << shift;
        rem = bc_rem;
        __syncthreads();
    }
    // prefix = T (exact bits of KSEL-th smallest d2); rem = #ties to take.

    float local = 0.0f;
#pragma unroll
    for (int p = 0; p < 4; ++p)
        if (uu[p] < prefix) local += __builtin_amdgcn_sqrtf(__uint_as_float(uu[p]));
#pragma unroll
    for (int off = 32; off > 0; off >>= 1) local += __shfl_down(local, off);
    if ((tid & 63) == 0) wred[tid >> 6] = local;

    float r = (tid < SL) ? repel_part[b * SL + tid] : 0.0f;
#pragma unroll
    for (int off = 32; off > 0; off >>= 1) r += __shfl_down(r, off);
    if ((tid & 63) == 0) wred2[tid >> 6] = r;
    __syncthreads();

    if (tid == 0) {
        const float total = wred[0] + wred[1] + wred[2] + wred[3]
                          + (float)rem * __builtin_amdgcn_sqrtf(__uint_as_float(prefix));
        const float rp = wred2[0] + wred2[1] + wred2[2] + wred2[3];
        out[b] = 10.0f * (total / (float)KSEL) + 5.0f * rp;
    }
}

extern "C" void kernel_launch(void* const* d_in, const int* in_sizes, int n_in,
                              void* d_out, int out_size, void* d_ws, size_t ws_size,
                              hipStream_t stream) {
    const float* binder = (const float*)d_in[0];   // [16,1024,3] fp32
    const float* target = (const float*)d_in[1];   // [8192,3]   fp32
    float* out = (float*)d_out;                    // [16]       fp32

    // workspace: min_part 2MB + repel_part 2KB
    float* min_part   = (float*)d_ws;
    float* repel_part = (float*)((char*)d_ws + (size_t)BB * SL * NN * sizeof(float));

    dim3 g1(SL, BB);   // 32 x 16 = 512 blocks -> 2 blocks/CU, 8 waves/CU
    binder_pair_kernel<<<g1, 256, 0, stream>>>(binder, target, min_part, repel_part);
    binder_reduce_kernel<<<BB, 256, 0, stream>>>(min_part, repel_part, out);
}

// Round 6
// 89.119 us; speedup vs baseline: 1.3764x; 1.1481x over previous
//
#include <hip/hip_runtime.h>

// B=16, N=1024, M=8192.
//   d[b,n,m] = || binder[b,n,:] - target[m,:] ||
//   attract[b] = mean of 204 smallest (min_m d) over n;  repel[b] = sum relu(3-d)^2
//   out[b] = 10*attract + 5*repel
//
// R8 (R7 post-mortem: atomic theory DEAD -- removing all atomics left pair at
// 45us. Matrix: R4 = lean loop + atomics + 8 w/SIMD = 45us (atomic-drain
// throttled block turnover); R7 = lean loop + no atomics + 2 w/SIMD = 45us
// (2 waves can't hide ~120cy LDS broadcast latency; VALUBusy 38% matches).
// Missing cell: lean loop + NO atomics + 8 w/SIMD):
//  - SL=128 slices of 64 targets: grid (128,16) = 2048 blocks, 256 thr,
//    launch_bounds(256,8) -> 8 blocks/CU, 8 waves/SIMD, 1KB LDS.
//  - plain coalesced float4 store of partial d^2 to min_part[B][SL][N] (8MB
//    streaming, no RMW, no memset).
//  - reduce folds 128 slice rows during load (coalesced float4, 512KB/block
//    from L2) then radix-256 selects on raw d^2 bits (nonneg -> monotonic).

#define BB 16
#define NN 1024
#define MM 8192
#define SL 128              // M-slices
#define MSL (MM / SL)       // 64 targets per slice
#define KSEL 204            // int(0.2 * 1024)

__global__ __launch_bounds__(256, 8) void binder_pair_kernel(
    const float* __restrict__ binder,    // [B, N, 3]
    const float* __restrict__ target,    // [M, 3]
    float* __restrict__ min_part,        // [B, SL, N] partial min d^2
    float* __restrict__ repel_part)      // [B, SL]
{
    __shared__ float4 t4[MSL];           // 1KB: (-2tx, -2ty, -2tz, ||t||^2)
    __shared__ float wred[4];

    const int s   = blockIdx.x;
    const int b   = blockIdx.y;
    const int tid = threadIdx.x;

    if (tid < MSL) {
        const float* tp = target + (size_t)(s * MSL + tid) * 3;
        const float tx = tp[0], ty = tp[1], tz = tp[2];
        t4[tid] = make_float4(-2.0f * tx, -2.0f * ty, -2.0f * tz,
                              fmaf(tx, tx, fmaf(ty, ty, tz * tz)));
    }
    __syncthreads();

    // 4 binder points per thread; 48B contiguous/lane, 16B-aligned.
    const float* bp = binder + ((size_t)b * NN + tid * 4) * 3;
    const float4 f0 = ((const float4*)bp)[0];
    const float4 f1 = ((const float4*)bp)[1];
    const float4 f2 = ((const float4*)bp)[2];
    const float x0 = f0.x, y0 = f0.y, z0 = f0.z;
    const float x1 = f0.w, y1 = f1.x, z1 = f1.y;
    const float x2 = f1.z, y2 = f1.w, z2 = f2.x;
    const float x3 = f2.y, y3 = f2.z, z3 = f2.w;

    const float bb0 = fmaf(x0, x0, fmaf(y0, y0, z0 * z0));
    const float bb1 = fmaf(x1, x1, fmaf(y1, y1, z1 * z1));
    const float bb2 = fmaf(x2, x2, fmaf(y2, y2, z2 * z2));
    const float bb3 = fmaf(x3, x3, fmaf(y3, y3, z3 * z3));
    const float th0 = 9.0f - bb0, th1 = 9.0f - bb1;
    const float th2 = 9.0f - bb2, th3 = 9.0f - bb3;

    float m0 = 3.4e38f, m1 = 3.4e38f, m2 = 3.4e38f, m3 = 3.4e38f;
    float repel = 0.0f;

#pragma unroll 4
    for (int m = 0; m < MSL; ++m) {
        const float4 t = t4[m];   // wave-uniform addr -> broadcast b128
        const float e0 = fmaf(x0, t.x, fmaf(y0, t.y, fmaf(z0, t.z, t.w)));
        const float e1 = fmaf(x1, t.x, fmaf(y1, t.y, fmaf(z1, t.z, t.w)));
        const float e2 = fmaf(x2, t.x, fmaf(y2, t.y, fmaf(z2, t.z, t.w)));
        const float e3 = fmaf(x3, t.x, fmaf(y3, t.y, fmaf(z3, t.z, t.w)));
        m0 = fminf(m0, e0);
        m1 = fminf(m1, e1);
        m2 = fminf(m2, e2);
        m3 = fminf(m3, e3);
        // per-point clash: e < 9-bb <=> d^2 < 9; non-clash lanes clamp to 0.
        if (__any(e0 < th0)) {
            const float c = fmaxf(3.0f - __builtin_amdgcn_sqrtf(fmaxf(bb0 + e0, 0.0f)), 0.0f);
            repel = fmaf(c, c, repel);
        }
        if (__any(e1 < th1)) {
            const float c = fmaxf(3.0f - __builtin_amdgcn_sqrtf(fmaxf(bb1 + e1, 0.0f)), 0.0f);
            repel = fmaf(c, c, repel);
        }
        if (__any(e2 < th2)) {
            const float c = fmaxf(3.0f - __builtin_amdgcn_sqrtf(fmaxf(bb2 + e2, 0.0f)), 0.0f);
            repel = fmaf(c, c, repel);
        }
        if (__any(e3 < th3)) {
            const float c = fmaxf(3.0f - __builtin_amdgcn_sqrtf(fmaxf(bb3 + e3, 0.0f)), 0.0f);
            repel = fmaf(c, c, repel);
        }
    }

    // plain coalesced store of this slice's partial min d^2 (no atomics)
    float4* op = (float4*)(min_part + ((size_t)b * SL + s) * NN) + tid;
    *op = make_float4(fmaxf(bb0 + m0, 0.0f), fmaxf(bb1 + m1, 0.0f),
                      fmaxf(bb2 + m2, 0.0f), fmaxf(bb3 + m3, 0.0f));

    // repel block-reduce: wave shuffle then 4-slot LDS
#pragma unroll
    for (int off = 32; off > 0; off >>= 1) repel += __shfl_down(repel, off);
    if ((tid & 63) == 0) wred[tid >> 6] = repel;
    __syncthreads();
    if (tid == 0) repel_part[b * SL + s] = wred[0] + wred[1] + wred[2] + wred[3];
}

__global__ __launch_bounds__(256) void binder_reduce_kernel(
    const float* __restrict__ min_part,    // [B, SL, N]
    const float* __restrict__ repel_part,  // [B, SL]
    float* __restrict__ out)               // [B]
{
    __shared__ int cnt[256];
    __shared__ int wsum[4];
    __shared__ int bc_bin, bc_rem;
    __shared__ float wred[4];
    __shared__ float wred2[4];

    const int b    = blockIdx.x;
    const int tid  = threadIdx.x;
    const int lane = tid & 63;
    const int wid  = tid >> 6;

    // fold the SL slice partials during load (each iter = one coalesced 4KB row)
    const float* base = min_part + (size_t)b * SL * NN;
    float mn0 = 3.4e38f, mn1 = 3.4e38f, mn2 = 3.4e38f, mn3 = 3.4e38f;
#pragma unroll 8
    for (int s = 0; s < SL; ++s) {
        const float4 v = ((const float4*)(base + (size_t)s * NN))[tid];
        mn0 = fminf(mn0, v.x);
        mn1 = fminf(mn1, v.y);
        mn2 = fminf(mn2, v.z);
        mn3 = fminf(mn3, v.w);
    }
    const unsigned uu[4] = {__float_as_uint(mn0), __float_as_uint(mn1),
                            __float_as_uint(mn2), __float_as_uint(mn3)};

    // radix-256 select of the KSEL-th smallest d^2 bit pattern, MSB-first.
    // scan per round: intra-wave __shfl_up inclusive scan (no barriers) +
    // 4-entry wave-sum combine -> 4 barriers/round.
    unsigned prefix = 0u;
    int rem = KSEL;
#pragma unroll
    for (int shift = 24; shift >= 0; shift -= 8) {
        cnt[tid] = 0;
        __syncthreads();
        const unsigned hmask = (shift == 24) ? 0u : (0xFFFFFFFFu << (shift + 8));
#pragma unroll
        for (int p = 0; p < 4; ++p)
            if ((uu[p] & hmask) == (prefix & hmask))
                atomicAdd(&cnt[(uu[p] >> shift) & 255], 1);
        __syncthreads();
        const int orig = cnt[tid];
        int v = orig;
#pragma unroll
        for (int s = 1; s < 64; s <<= 1) {
            const int t = __shfl_up(v, s);
            if (lane >= s) v += t;
        }
        if (lane == 63) wsum[wid] = v;
        __syncthreads();
        int off = 0;
        for (int w = 0; w < wid; ++w) off += wsum[w];
        const int incl = v + off;
        const int excl = incl - orig;
        if (rem > excl && rem <= incl) {   // unique tid (orig>0 there)
            bc_bin = tid;
            bc_rem = rem - excl;
        }
        __syncthreads();
        prefix |= ((unsigned)bc_bin) << shift;
        rem = bc_rem;
        __syncthreads();
    }
    // prefix = T (exact bits of KSEL-th smallest d2); rem = #ties to take.

    float local = 0.0f;
#pragma unroll
    for (int p = 0; p < 4; ++p)
        if (uu[p] < prefix) local += __builtin_amdgcn_sqrtf(__uint_as_float(uu[p]));
#pragma unroll
    for (int off = 32; off > 0; off >>= 1) local += __shfl_down(local, off);
    if ((tid & 63) == 0) wred[tid >> 6] = local;

    float r = (tid < SL) ? repel_part[b * SL + tid] : 0.0f;
#pragma unroll
    for (int off = 32; off > 0; off >>= 1) r += __shfl_down(r, off);
    if ((tid & 63) == 0) wred2[tid >> 6] = r;
    __syncthreads();

    if (tid == 0) {
        const float total = wred[0] + wred[1] + wred[2] + wred[3]
                          + (float)rem * __builtin_amdgcn_sqrtf(__uint_as_float(prefix));
        const float rp = wred2[0] + wred2[1] + wred2[2] + wred2[3];
        out[b] = 10.0f * (total / (float)KSEL) + 5.0f * rp;
    }
}

extern "C" void kernel_launch(void* const* d_in, const int* in_sizes, int n_in,
                              void* d_out, int out_size, void* d_ws, size_t ws_size,
                              hipStream_t stream) {
    const float* binder = (const float*)d_in[0];   // [16,1024,3] fp32
    const float* target = (const float*)d_in[1];   // [8192,3]   fp32
    float* out = (float*)d_out;                    // [16]       fp32

    // workspace: min_part 8MB + repel_part 8KB
    float* min_part   = (float*)d_ws;
    float* repel_part = (float*)((char*)d_ws + (size_t)BB * SL * NN * sizeof(float));

    dim3 g1(SL, BB);   // 128 x 16 = 2048 blocks -> 8 blocks/CU, 8 waves/SIMD
    binder_pair_kernel<<<g1, 256, 0, stream>>>(binder, target, min_part, repel_part);
    binder_reduce_kernel<<<BB, 256, 0, stream>>>(min_part, repel_part, out);
}